// Round 3
// baseline (512.930 us; speedup 1.0000x reference)
//
#include <hip/hip_runtime.h>

// Guided filter r=8, eps=1e-4, (1,3,4096,4096) fp32.
// Wave-autonomous streaming, 2 columns per lane (packed fp32):
//  - lane owns adjacent column pair (2l, 2l+1); 128 cols/wave, 112 outputs
//  - per-column vertical 17-row running sums kept as v2f (v_pk_*_f32)
//  - horizontal 17-tap window from ONE wave scan of pair-sums:
//      CP(2l+1) = P(l), CP(2l) = P(l) - v1(l) = Q(l)
//      w(2l)   = Q(l+4) - [l>=5] P(l-5)
//      w(2l+1) = P(l+4) - [l>=4] Q(l-4)
//  - explicit 1-row software prefetch hides HBM latency under scan+epilogue
//  - dwordx2 loads/stores (512 B per wave instruction)

typedef float v2f __attribute__((ext_vector_type(2)));

#define HH   4096
#define WW   4096
#define CC   3
#define RAD  8
#define LOG2W 12
#define OUTC 112           // output columns per wave
#define ROWS 35            // output rows per wave tile (1 + 2*17)
#define CS   37            // ceil(4096/112) column strips
#define RS   118           // ceil(4096/35) row strips
#define TOTALW (CC*CS*RS)  // 13098
#define WPB  4             // waves per 256-thread block
#define EPS  1e-4f

// Four wave64 inclusive prefix sums, fused-DPP, 4-way interleaved (proven in r2).
__device__ __forceinline__ void scan4(float si, float sp, float spi, float sii,
                                      float& a, float& b, float& c, float& d) {
    asm("v_mov_b32 %0, %4\n\t"
        "v_mov_b32 %1, %5\n\t"
        "v_mov_b32 %2, %6\n\t"
        "v_mov_b32 %3, %7\n\t"
        "v_add_f32_dpp %0, %0, %0 row_shr:1 row_mask:0xf bank_mask:0xf bound_ctrl:0\n\t"
        "v_add_f32_dpp %1, %1, %1 row_shr:1 row_mask:0xf bank_mask:0xf bound_ctrl:0\n\t"
        "v_add_f32_dpp %2, %2, %2 row_shr:1 row_mask:0xf bank_mask:0xf bound_ctrl:0\n\t"
        "v_add_f32_dpp %3, %3, %3 row_shr:1 row_mask:0xf bank_mask:0xf bound_ctrl:0\n\t"
        "v_add_f32_dpp %0, %0, %0 row_shr:2 row_mask:0xf bank_mask:0xf bound_ctrl:0\n\t"
        "v_add_f32_dpp %1, %1, %1 row_shr:2 row_mask:0xf bank_mask:0xf bound_ctrl:0\n\t"
        "v_add_f32_dpp %2, %2, %2 row_shr:2 row_mask:0xf bank_mask:0xf bound_ctrl:0\n\t"
        "v_add_f32_dpp %3, %3, %3 row_shr:2 row_mask:0xf bank_mask:0xf bound_ctrl:0\n\t"
        "v_add_f32_dpp %0, %0, %0 row_shr:4 row_mask:0xf bank_mask:0xf bound_ctrl:0\n\t"
        "v_add_f32_dpp %1, %1, %1 row_shr:4 row_mask:0xf bank_mask:0xf bound_ctrl:0\n\t"
        "v_add_f32_dpp %2, %2, %2 row_shr:4 row_mask:0xf bank_mask:0xf bound_ctrl:0\n\t"
        "v_add_f32_dpp %3, %3, %3 row_shr:4 row_mask:0xf bank_mask:0xf bound_ctrl:0\n\t"
        "v_add_f32_dpp %0, %0, %0 row_shr:8 row_mask:0xf bank_mask:0xf bound_ctrl:0\n\t"
        "v_add_f32_dpp %1, %1, %1 row_shr:8 row_mask:0xf bank_mask:0xf bound_ctrl:0\n\t"
        "v_add_f32_dpp %2, %2, %2 row_shr:8 row_mask:0xf bank_mask:0xf bound_ctrl:0\n\t"
        "v_add_f32_dpp %3, %3, %3 row_shr:8 row_mask:0xf bank_mask:0xf bound_ctrl:0\n\t"
        "v_add_f32_dpp %0, %0, %0 row_bcast:15 row_mask:0xa bank_mask:0xf\n\t"
        "v_add_f32_dpp %1, %1, %1 row_bcast:15 row_mask:0xa bank_mask:0xf\n\t"
        "v_add_f32_dpp %2, %2, %2 row_bcast:15 row_mask:0xa bank_mask:0xf\n\t"
        "v_add_f32_dpp %3, %3, %3 row_bcast:15 row_mask:0xa bank_mask:0xf\n\t"
        "v_add_f32_dpp %0, %0, %0 row_bcast:31 row_mask:0xc bank_mask:0xf\n\t"
        "v_add_f32_dpp %1, %1, %1 row_bcast:31 row_mask:0xc bank_mask:0xf\n\t"
        "v_add_f32_dpp %2, %2, %2 row_bcast:31 row_mask:0xc bank_mask:0xf\n\t"
        "v_add_f32_dpp %3, %3, %3 row_bcast:31 row_mask:0xc bank_mask:0xf"
        : "=&v"(a), "=&v"(b), "=&v"(c), "=&v"(d)
        : "v"(si), "v"(sp), "v"(spi), "v"(sii));
}

__device__ __forceinline__ float bper(int addr, float x) {
    return __int_as_float(__builtin_amdgcn_ds_bpermute(addr, __float_as_int(x)));
}

__global__ __launch_bounds__(256, 4)
void gf_stream_kernel(const float* __restrict__ gi,
                      const float* __restrict__ gp,
                      float* __restrict__ gq) {
    const int lane = threadIdx.x & 63;
    const int wid  = __builtin_amdgcn_readfirstlane(blockIdx.x * WPB + (threadIdx.x >> 6));
    if (wid >= TOTALW) return;             // wave-uniform tail exit (no barriers anywhere)

    const int c   = wid / (CS * RS);
    const int rm  = wid - c * (CS * RS);
    const int rs  = rm / CS;
    const int cs  = rm - rs * CS;
    const int xb  = cs * OUTC - RAD;       // strip base column; always even
    const int y0  = rs * ROWS;

    const size_t plane = (size_t)HH << LOG2W;
    const float* Ic = gi + (size_t)c * plane;
    const float* Pc = gp + (size_t)c * plane;
    float*       Qc = gq + (size_t)c * plane;

    // column pair: gx0 = xb + 2*lane (even), gx1 = gx0+1. Since xb and WW are
    // even, the pair is valid all-or-nothing.
    const int  gx0 = xb + 2 * lane;
    const bool pv  = (gx0 >= 0) && (gx0 < WW);
    const int  gxc = min(max(gx0, 0), WW - 2);      // clamped dwordx2-safe base
    const bool outok = (lane >= 4) && (lane < 60) && pv;

    // bpermute byte addresses + border masks for the window taps
    const int   adn = ((lane + 4) & 63) << 2;
    const int   au5 = ((lane - 5) & 63) << 2;
    const int   au4 = ((lane - 4) & 63) << 2;
    const float m5  = (lane >= 5) ? -1.0f : 0.0f;
    const float m4  = (lane >= 4) ? -1.0f : 0.0f;

    const int gx1 = gx0 + 1;
    const int nx0 = min(gx0 + RAD, WW - 1) - max(gx0 - RAD, 0) + 1;
    const int nx1 = min(gx1 + RAD, WW - 1) - max(gx1 - RAD, 0) + 1;
    v2f invnx;
    invnx.x = __builtin_amdgcn_rcpf((float)max(nx0, 1));
    invnx.y = __builtin_amdgcn_rcpf((float)max(nx1, 1));

    const v2f zero = {0.f, 0.f};
    v2f bi[17], bp[17];
    v2f vsi = zero, vsp = zero, vspi = zero, vsii = zero;

    // ---- init: rows y0-8 .. y0+8 into circular buffer slots 0..16 ----
#pragma unroll
    for (int k = 0; k < 17; ++k) {
        int yy = y0 - RAD + k;
        v2f a = zero, b = zero;
        if (yy >= 0 && yy < HH) {          // wave-uniform
            const float* rI = Ic + ((size_t)(unsigned)yy << LOG2W);
            const float* rP = Pc + ((size_t)(unsigned)yy << LOG2W);
            v2f av = *reinterpret_cast<const v2f*>(rI + gxc);
            v2f bv = *reinterpret_cast<const v2f*>(rP + gxc);
            a = pv ? av : zero;
            b = pv ? bv : zero;
        }
        bi[k] = a; bp[k] = b;
        vsi += a; vsp += b;
        vspi = __builtin_elementwise_fma(a, b, vspi);
        vsii = __builtin_elementwise_fma(a, a, vsii);
    }

    // ---- software prefetch: row y0+9 (consumed by first loop iteration) ----
    v2f pfa = zero, pfb = zero;
    {
        int py = y0 + RAD + 1;
        if (py < HH) {                     // wave-uniform
            const float* rI = Ic + ((size_t)(unsigned)py << LOG2W);
            const float* rP = Pc + ((size_t)(unsigned)py << LOG2W);
            pfa = *reinterpret_cast<const v2f*>(rI + gxc);
            pfb = *reinterpret_cast<const v2f*>(rP + gxc);
        }
    }

    // ---- emit one output row (pair of output columns per lane) ----
    auto emit = [&](int y, v2f icur) {
        float psi  = vsi.x  + vsi.y;
        float psp  = vsp.x  + vsp.y;
        float pspi = vspi.x + vspi.y;
        float psii = vsii.x + vsii.y;
        float Pi_, Pp_, Ppi_, Pii_;
        scan4(psi, psp, pspi, psii, Pi_, Pp_, Ppi_, Pii_);
        float Qi_  = Pi_  - vsi.y;         // CP at this lane's even column
        float Qp_  = Pp_  - vsp.y;
        float Qpi_ = Ppi_ - vspi.y;
        float Qii_ = Pii_ - vsii.y;

        auto taps = [&](float P_, float Q_) -> v2f {
            float qdn = bper(adn, Q_);     // CP(2l+8)
            float pdn = bper(adn, P_);     // CP(2l+9)
            float pu5 = bper(au5, P_);     // CP(2l-9)
            float qu4 = bper(au4, Q_);     // CP(2l-8)
            v2f w;
            w.x = fmaf(m5, pu5, qdn);      // window for col 2l
            w.y = fmaf(m4, qu4, pdn);      // window for col 2l+1
            return w;
        };
        v2f wi  = taps(Pi_,  Qi_);
        v2f wp  = taps(Pp_,  Qp_);
        v2f wpi = taps(Ppi_, Qpi_);
        v2f wii = taps(Pii_, Qii_);

        int   ny  = min(y + RAD, HH - 1) - max(y - RAD, 0) + 1;   // uniform
        float iny = __builtin_amdgcn_rcpf((float)ny);
        v2f invN  = invnx * iny;
        v2f mi  = wi  * invN;
        v2f mp  = wp  * invN;
        v2f mpi = wpi * invN;
        v2f mii = wii * invN;
        v2f cip = __builtin_elementwise_fma(-mp, mi, mpi);
        v2f cii = __builtin_elementwise_fma(-mi, mi, mii);
        v2f den = cii + EPS;
        v2f ra;
        ra.x = __builtin_amdgcn_rcpf(den.x);
        ra.y = __builtin_amdgcn_rcpf(den.y);
        v2f aa = cip * ra;
        v2f bb = __builtin_elementwise_fma(-aa, mi, mp);
        v2f q  = __builtin_elementwise_fma(aa, icur, bb);
        q = __builtin_elementwise_min(__builtin_elementwise_max(q, zero), (v2f){1.f, 1.f});
        if (outok) {
            float* Qrow = Qc + ((size_t)(unsigned)y << LOG2W);
            *reinterpret_cast<v2f*>(Qrow + gx0) = q;
        }
    };

    emit(y0, bi[8]);                       // t = 0 (current row slot = 8); y0 < HH always

    int y = y0;
#pragma unroll 1
    for (int o = 0; o < 2; ++o) {
#pragma unroll
        for (int u = 0; u < 17; ++u) {
            ++y;                           // output row y = y0 + t
            // outgoing row (y-9) lives in slot u
            v2f a0 = bi[u], b0 = bp[u];
            vsi -= a0; vsp -= b0;
            vspi = __builtin_elementwise_fma(-a0, b0, vspi);
            vsii = __builtin_elementwise_fma(-a0, a0, vsii);

            // incoming row (y+8) was prefetched last iteration
            v2f na = pv ? pfa : zero;
            v2f nb = pv ? pfb : zero;
            bi[u] = na; bp[u] = nb;
            vsi += na; vsp += nb;
            vspi = __builtin_elementwise_fma(na, nb, vspi);
            vsii = __builtin_elementwise_fma(na, na, vsii);

            // issue next prefetch (row y+9) BEFORE scan+epilogue so the load
            // latency hides under the compute of this row
            int py = y + RAD + 1;
            if (py < HH) {                 // wave-uniform
                const float* rI = Ic + ((size_t)(unsigned)py << LOG2W);
                const float* rP = Pc + ((size_t)(unsigned)py << LOG2W);
                pfa = *reinterpret_cast<const v2f*>(rI + gxc);
                pfb = *reinterpret_cast<const v2f*>(rP + gxc);
            } else { pfa = zero; pfb = zero; }

            if (y < HH)                    // wave-uniform (bottom strip trims)
                emit(y, bi[(u + 9) % 17]); // current row y sits in slot (u+9)%17
        }
    }
}

extern "C" void kernel_launch(void* const* d_in, const int* in_sizes, int n_in,
                              void* d_out, int out_size, void* d_ws, size_t ws_size,
                              hipStream_t stream) {
    const float* gi = (const float*)d_in[0];
    const float* gp = (const float*)d_in[1];
    float* gq = (float*)d_out;
    const int blocks = (TOTALW + WPB - 1) / WPB;   // 3275
    gf_stream_kernel<<<blocks, 256, 0, stream>>>(gi, gp, gq);
}